// Round 10
// baseline (361.007 us; speedup 1.0000x reference)
//
#include <hip/hip_runtime.h>
#include <stdint.h>

typedef __attribute__((ext_vector_type(8))) short short8_t;
typedef __attribute__((ext_vector_type(4))) float f32x4_t;

#define THETA 12.0f
#define EPS 1e-8f
#define CAND_TARGET 11  // non-self candidates kept by threshold (need >= 9)
#define NC_CAP 13       // non-self candidate cap

__device__ __forceinline__ unsigned short f2bf(float f) {
  unsigned int u = __float_as_uint(f);
  u = (u + 0x7fffu + ((u >> 16) & 1u)) >> 16;
  return (unsigned short)u;
}
__device__ __forceinline__ unsigned umax_(unsigned a, unsigned b) { return a > b ? a : b; }
__device__ __forceinline__ unsigned umin_(unsigned a, unsigned b) { return a < b ? a : b; }
__device__ __forceinline__ unsigned sx(unsigned v, int m) {
  return (unsigned)__shfl_xor((int)v, m);
}
__device__ __forceinline__ void load_lds16(const void* g, void* l) {
  __builtin_amdgcn_global_load_lds((const __attribute__((address_space(1))) void*)g,
                                   (__attribute__((address_space(3))) void*)l, 16, 0, 0);
}

// K1: bf16 row-normalized copy. One wave per row.
__global__ __launch_bounds__(256) void k_norm(const float* __restrict__ h,
                                              unsigned short* __restrict__ hnb, int n) {
  const int row = blockIdx.x * 4 + (threadIdx.x >> 6);
  const int lane = threadIdx.x & 63;
  if (row >= n) return;
  const float2 hv = *(const float2*)(h + (size_t)row * 128 + lane * 2);
  float ss = hv.x * hv.x + hv.y * hv.y;
  #pragma unroll
  for (int o = 32; o > 0; o >>= 1) ss += __shfl_xor(ss, o);
  const float rn = 1.0f / fmaxf(sqrtf(ss), EPS);
  const unsigned int b0 = f2bf(hv.x * rn), b1 = f2bf(hv.y * rn);
  *(unsigned int*)(hnb + (size_t)row * 128 + lane * 2) = b0 | (b1 << 16);
}

// K2 v10: A-fragments loaded DIRECTLY global->registers (hnb is L2-resident;
// 16 b128 gathers/lane), only B staged in LDS (32 KB -> 5 blocks/CU, 20
// waves/CU). acc init = 2.0f so acc = sim+2 is positive -> raw bits monotone.
// Epilogue: top-1 per 32-col half-group, packed (key16<<16)|(N-1-col),
// cand[g][r] = uint2{top of cols 0-31, top of cols 32-63}.
__global__ __launch_bounds__(256, 5) void k_gemm(const unsigned short* __restrict__ hnb,
                                                 uint2* __restrict__ cand, int nAll) {
  __shared__ __align__(16) char Bs[32768];
  const int tid = threadIdx.x;
  const int wid = tid >> 6, lane = tid & 63;
  const int l15 = lane & 15, lhi = lane >> 4;
  const int wr = wid >> 1, wc = wid & 1;

  const char* gA = (const char*)hnb + (size_t)(blockIdx.y * 128) * 256;
  const char* gB = (const char*)hnb + (size_t)(blockIdx.x * 128) * 256;

  // A fragments: af[m][kk] = 16 bytes of row (wr*64+m*16+l15) at k-offset
  // kk*64+lhi*16. Issued upfront; latency hides under B staging + barrier.
  short8_t af[4][4];
  #pragma unroll
  for (int m = 0; m < 4; ++m) {
    const char* rp = gA + (wr * 64 + m * 16 + l15) * 256 + lhi * 16;
    #pragma unroll
    for (int kk = 0; kk < 4; ++kk)
      af[m][kk] = *(const short8_t*)(rp + kk * 64);
  }

  // B staging (swizzled source -> linear LDS; read-side XOR restores).
  #pragma unroll
  for (int it = 0; it < 8; ++it) {
    const int ob = it * 4096 + tid * 16;
    const int row = ob >> 8;
    const int sbc = (ob & 255) ^ ((row & 7) << 4);
    load_lds16(gB + row * 256 + sbc, Bs + it * 4096 + wid * 1024);
  }
  __syncthreads();

  f32x4_t acc[4][4];
  #pragma unroll
  for (int m = 0; m < 4; ++m)
    #pragma unroll
    for (int nn = 0; nn < 4; ++nn)
      acc[m][nn] = (f32x4_t){2.0f, 2.0f, 2.0f, 2.0f};
  #pragma unroll
  for (int kk = 0; kk < 4; ++kk) {
    short8_t bfr[4];
    #pragma unroll
    for (int nn = 0; nn < 4; ++nn) {
      const int row = wc * 64 + nn * 16 + l15;
      const int addr = row * 256 + ((kk * 64 + lhi * 16) ^ ((row & 7) << 4));
      bfr[nn] = *(const short8_t*)(Bs + addr);
    }
    #pragma unroll
    for (int m = 0; m < 4; ++m)
      #pragma unroll
      for (int nn = 0; nn < 4; ++nn)
        acc[m][nn] = __builtin_amdgcn_mfma_f32_16x16x32_bf16(bfr[nn], af[m][kk], acc[m][nn], 0, 0, 0);
  }

  // Epilogue: lane's 16 values for row wr*64+m*16+l15 are cols
  // bx*128 + wc*64 + nn*16 + lhi*4 + j. Half A = nn in {0,1}, half B = {2,3}.
  const unsigned ccbase = (unsigned)(nAll - 1 - (blockIdx.x * 128 + wc * 64 + lhi * 4));
  unsigned ccnj[16];
  #pragma unroll
  for (int nn = 0; nn < 4; ++nn)
    #pragma unroll
    for (int j = 0; j < 4; ++j) ccnj[nn * 4 + j] = ccbase - (unsigned)(nn * 16 + j);
  #pragma unroll
  for (int m = 0; m < 4; ++m) {
    unsigned a = 0, b = 0;
    #pragma unroll
    for (int nn = 0; nn < 2; ++nn)
      #pragma unroll
      for (int j = 0; j < 4; ++j)
        a = umax_(a, (__float_as_uint(acc[m][nn][j]) & 0xFFFF0000u) | ccnj[nn * 4 + j]);
    #pragma unroll
    for (int nn = 2; nn < 4; ++nn)
      #pragma unroll
      for (int j = 0; j < 4; ++j)
        b = umax_(b, (__float_as_uint(acc[m][nn][j]) & 0xFFFF0000u) | ccnj[nn * 4 + j]);
    a = umax_(a, sx(a, 16)); a = umax_(a, sx(a, 32));
    b = umax_(b, sx(b, 16)); b = umax_(b, sx(b, 32));
    if (lhi == 0) {
      const int grow = blockIdx.y * 128 + wr * 64 + m * 16 + l15;
      const int g = blockIdx.x * 2 + wc;
      uint2 v; v.x = a; v.y = b;
      cand[(size_t)g * nAll + grow] = v;
    }
  }
}

// K3 v10: 512-thread block = 8 waves = 8 consecutive rows. Coalesced staging
// into swizzled LDS; FIXED-BOUNDS branch-free 8-iter threshold search
// (key = sim+2 in [1,3] -> [0x3F80, 0x4040], range 193 < 256); ONE-PASS
// compaction (cap overflow drops only tie-grade candidates, beta <= 7e-4);
// softmax over kept candidates with key-decoded sims + self at weight 1.
__global__ __launch_bounds__(512) void k_select(const uint2* __restrict__ cand,
                                                const float* __restrict__ h,
                                                float* __restrict__ out, int nAll) {
  __shared__ unsigned pkx[2048];   // [g][rl] u32, slot = g*8 + (rl ^ ((g>>2)&7))
  __shared__ unsigned pky[2048];
  __shared__ unsigned s_p[8][16];  // packed kept candidates per wave
  const int t = threadIdx.x;
  const int lane = t & 63, wid = t >> 6;
  const int r0 = blockIdx.x * 8;
  const int r = r0 + wid;          // this wave's row
  const unsigned long long ltmask = (1ull << lane) - 1ull;

  if (lane < 16) s_p[wid][lane] = 0;  // pads: key 0 -> sim -2 -> weight ~0

  // Stage: 4 passes x 512 threads; 8 consecutive rows per 64-B line.
  #pragma unroll
  for (int p = 0; p < 4; ++p) {
    const int g = p * 64 + (t >> 3);
    const int rl = t & 7;
    const uint2 q = cand[(size_t)g * nAll + r0 + rl];
    const int slot = g * 8 + (rl ^ ((g >> 2) & 7));
    pkx[slot] = q.x; pky[slot] = q.y;
  }
  __syncthreads();

  // Phase 1: 8 packed candidates per lane from LDS (2-way reads, free).
  unsigned pk[8];
  #pragma unroll
  for (int i = 0; i < 4; ++i) {
    const int g = i * 64 + lane;
    const int slot = g * 8 + (wid ^ ((g >> 2) & 7));
    pk[i * 2 + 0] = pkx[slot];
    pk[i * 2 + 1] = pky[slot];
  }
  const unsigned selfpat = (unsigned)(nAll - 1 - r);
  #pragma unroll
  for (int i = 0; i < 8; ++i) if ((pk[i] & 0xFFFFu) == selfpat) pk[i] = 0;

  // Phase 2: fixed-bounds branch-free binary search for largest t2 with
  // count(key16 >= t2) >= CAND_TARGET. Invariants hold at init: all ~510
  // non-self keys >= 0x3F80 (cos >= -1); no key can exceed 0x4040 (cos < 1).
  unsigned lo = 0x3F80u, hi = 0x4040u;
  #pragma unroll
  for (int it = 0; it < 8; ++it) {
    const unsigned mid = (lo + hi + 1) >> 1;
    int c = 0;
    #pragma unroll
    for (int i = 0; i < 8; ++i) c += __popcll(__ballot((pk[i] >> 16) >= mid));
    const bool ge = c >= CAND_TARGET;
    lo = ge ? mid : lo;
    hi = ge ? hi : mid - 1;
  }
  const unsigned t2 = lo;

  // Phase 3: one-pass compaction of packed entries >= t2 (self slots are 0 <
  // t2, auto-excluded). Strict-> always <= 10; overflow drops only ties.
  {
    int base = 0;
    #pragma unroll
    for (int i = 0; i < 8; ++i) {
      const bool p = (pk[i] >> 16) >= t2;
      const unsigned long long m = __ballot(p);
      const int pos = base + __popcll(m & ltmask);
      if (p && pos < NC_CAP) s_p[wid][pos] = pk[i];
      base += __popcll(m);
    }
  }

  // Phase 4: softmax over self (sim 1.0) + kept candidates, sims decoded
  // from keys: sim = as_float(key16 << 16) - 2. Pads: sim = -2 -> w ~ 0.
  float w[NC_CAP]; int cidx[NC_CAP];
  float z = 1.0f;
  #pragma unroll
  for (int i = 0; i < NC_CAP; ++i) {
    const unsigned p = s_p[wid][i];
    const float sim = __uint_as_float(p & 0xFFFF0000u) - 2.0f;
    w[i] = __expf(THETA * (sim - 1.0f));
    cidx[i] = nAll - 1 - (int)(p & 0xFFFFu);
    z += w[i];
  }
  const float rz = 1.0f / z;

  // Phase 5: fp32 weighted aggregation (self + 13 gathers, 512 B coalesced).
  const float2 hr = *(const float2*)(h + (size_t)r * 128 + lane * 2);
  float ax = hr.x, ay = hr.y;
  #pragma unroll
  for (int k = 0; k < NC_CAP; ++k) {
    const float2 hc = *(const float2*)(h + (size_t)cidx[k] * 128 + lane * 2);
    ax += w[k] * hc.x; ay += w[k] * hc.y;
  }
  float2 o2; o2.x = ax * rz; o2.y = ay * rz;
  *(float2*)(out + (size_t)r * 128 + lane * 2) = o2;
}

extern "C" void kernel_launch(void* const* d_in, const int* in_sizes, int n_in,
                              void* d_out, int out_size, void* d_ws, size_t ws_size,
                              hipStream_t stream) {
  const float* h = (const float*)d_in[0];
  float* out = (float*)d_out;
  const int N = in_sizes[0] / 128;  // 16384
  char* ws = (char*)d_ws;
  unsigned short* hnb = (unsigned short*)ws;         // N*128 bf16 = 4 MiB
  size_t off = ((size_t)N * 256 + 511) & ~(size_t)511;
  uint2* cand = (uint2*)(ws + off);                  // [G][N] uint2 = 32 MiB

  hipLaunchKernelGGL(k_norm, dim3((N + 3) / 4), dim3(256), 0, stream, h, hnb, N);
  hipLaunchKernelGGL(k_gemm, dim3(N / 128, N / 128), dim3(256), 0, stream, hnb, cand, N);
  hipLaunchKernelGGL(k_select, dim3(N / 8), dim3(512), 0, stream, cand, h, out, N);
}

// Round 11
// 165.024 us; speedup vs baseline: 2.1876x; 2.1876x over previous
//
#include <hip/hip_runtime.h>
#include <stdint.h>

typedef __attribute__((ext_vector_type(8))) short short8_t;
typedef __attribute__((ext_vector_type(4))) float f32x4_t;

#define THETA 12.0f
#define EPS 1e-8f
#define CAND_TARGET 11  // non-self candidates kept by threshold (need >= 9)
#define NC_CAP 13       // non-self candidate cap

__device__ __forceinline__ unsigned short f2bf(float f) {
  unsigned int u = __float_as_uint(f);
  u = (u + 0x7fffu + ((u >> 16) & 1u)) >> 16;
  return (unsigned short)u;
}
__device__ __forceinline__ unsigned umax_(unsigned a, unsigned b) { return a > b ? a : b; }
__device__ __forceinline__ unsigned umin_(unsigned a, unsigned b) { return a < b ? a : b; }
__device__ __forceinline__ unsigned sx(unsigned v, int m) {
  return (unsigned)__shfl_xor((int)v, m);
}
__device__ __forceinline__ void load_lds16(const void* g, void* l) {
  __builtin_amdgcn_global_load_lds((const __attribute__((address_space(1))) void*)g,
                                   (__attribute__((address_space(3))) void*)l, 16, 0, 0);
}

// K1: bf16 row-normalized copy. One wave per row.
__global__ __launch_bounds__(256) void k_norm(const float* __restrict__ h,
                                              unsigned short* __restrict__ hnb, int n) {
  const int row = blockIdx.x * 4 + (threadIdx.x >> 6);
  const int lane = threadIdx.x & 63;
  if (row >= n) return;
  const float2 hv = *(const float2*)(h + (size_t)row * 128 + lane * 2);
  float ss = hv.x * hv.x + hv.y * hv.y;
  #pragma unroll
  for (int o = 32; o > 0; o >>= 1) ss += __shfl_xor(ss, o);
  const float rn = 1.0f / fmaxf(sqrtf(ss), EPS);
  const unsigned int b0 = f2bf(hv.x * rn), b1 = f2bf(hv.y * rn);
  *(unsigned int*)(hnb + (size_t)row * 128 + lane * 2) = b0 | (b1 << 16);
}

// K2 v11: 128x128 tile, K split into two 64-wide halves, SINGLE-buffered
// 32 KB LDS (A[128][64] + B[128][64]) -> 4-5 blocks/CU (vs 2 at 64 KB).
// Both operands LDS-staged (r10's A-in-reg spilled: 128 VGPRs of fragments).
// acc init = 2.0f so acc = sim+2 is positive -> raw bits monotone.
// Epilogue: top-1 per 32-col half-group, packed (key16<<16)|(N-1-col).
__global__ __launch_bounds__(256, 4) void k_gemm(const unsigned short* __restrict__ hnb,
                                                 uint2* __restrict__ cand, int nAll) {
  __shared__ __align__(16) char lds[32768];
  char* As = lds;            // [128 rows][128 B] bf16, XOR-swizzled
  char* Bs = lds + 16384;
  const int tid = threadIdx.x;
  const int wid = tid >> 6, lane = tid & 63;
  const int l15 = lane & 15, lhi = lane >> 4;
  const int wr = wid >> 1, wc = wid & 1;

  const char* gA = (const char*)hnb + (size_t)(blockIdx.y * 128) * 256;
  const char* gB = (const char*)hnb + (size_t)(blockIdx.x * 128) * 256;

  f32x4_t acc[4][4];
  #pragma unroll
  for (int m = 0; m < 4; ++m)
    #pragma unroll
    for (int nn = 0; nn < 4; ++nn)
      acc[m][nn] = (f32x4_t){2.0f, 2.0f, 2.0f, 2.0f};

  #pragma unroll
  for (int ks = 0; ks < 2; ++ks) {
    // Stage this K-half: 4 iters x 4 KB per matrix (rows are 128 B).
    // LDS[row][bc] = G[row][ks*128 + (bc ^ swz(row))] (linear dest,
    // inverse-swizzled source; read-side XOR restores).
    #pragma unroll
    for (int it = 0; it < 4; ++it) {
      const int ob = it * 4096 + tid * 16;
      const int row = ob >> 7;
      const int sbc = (ob & 127) ^ ((row & 7) << 4);
      const int ldso = it * 4096 + wid * 1024;  // wave-uniform base
      load_lds16(gA + row * 256 + ks * 128 + sbc, As + ldso);
      load_lds16(gB + row * 256 + ks * 128 + sbc, Bs + ldso);
    }
    __syncthreads();
    #pragma unroll
    for (int kk = 0; kk < 2; ++kk) {
      short8_t af[4], bfr[4];
      #pragma unroll
      for (int m = 0; m < 4; ++m) {
        const int row = wr * 64 + m * 16 + l15;
        const int addr = row * 128 + ((kk * 64 + lhi * 16) ^ ((row & 7) << 4));
        af[m] = *(const short8_t*)(As + addr);
      }
      #pragma unroll
      for (int nn = 0; nn < 4; ++nn) {
        const int row = wc * 64 + nn * 16 + l15;
        const int addr = row * 128 + ((kk * 64 + lhi * 16) ^ ((row & 7) << 4));
        bfr[nn] = *(const short8_t*)(Bs + addr);
      }
      #pragma unroll
      for (int m = 0; m < 4; ++m)
        #pragma unroll
        for (int nn = 0; nn < 4; ++nn)
          acc[m][nn] = __builtin_amdgcn_mfma_f32_16x16x32_bf16(bfr[nn], af[m], acc[m][nn], 0, 0, 0);
    }
    __syncthreads();  // before next K-half overwrites the buffers
  }

  // Epilogue: lane's 16 values for row wr*64+m*16+l15 are cols
  // bx*128 + wc*64 + nn*16 + lhi*4 + j. Half A = nn in {0,1}, half B = {2,3}.
  const unsigned ccbase = (unsigned)(nAll - 1 - (blockIdx.x * 128 + wc * 64 + lhi * 4));
  unsigned ccnj[16];
  #pragma unroll
  for (int nn = 0; nn < 4; ++nn)
    #pragma unroll
    for (int j = 0; j < 4; ++j) ccnj[nn * 4 + j] = ccbase - (unsigned)(nn * 16 + j);
  #pragma unroll
  for (int m = 0; m < 4; ++m) {
    unsigned a = 0, b = 0;
    #pragma unroll
    for (int nn = 0; nn < 2; ++nn)
      #pragma unroll
      for (int j = 0; j < 4; ++j)
        a = umax_(a, (__float_as_uint(acc[m][nn][j]) & 0xFFFF0000u) | ccnj[nn * 4 + j]);
    #pragma unroll
    for (int nn = 2; nn < 4; ++nn)
      #pragma unroll
      for (int j = 0; j < 4; ++j)
        b = umax_(b, (__float_as_uint(acc[m][nn][j]) & 0xFFFF0000u) | ccnj[nn * 4 + j]);
    a = umax_(a, sx(a, 16)); a = umax_(a, sx(a, 32));
    b = umax_(b, sx(b, 16)); b = umax_(b, sx(b, 32));
    if (lhi == 0) {
      const int grow = blockIdx.y * 128 + wr * 64 + m * 16 + l15;
      const int g = blockIdx.x * 2 + wc;
      uint2 v; v.x = a; v.y = b;
      cand[(size_t)g * nAll + grow] = v;
    }
  }
}

// K3 v10 (unchanged): 512-thread block = 8 waves = 8 consecutive rows.
// Coalesced staging into swizzled LDS; fixed-bounds branch-free 8-iter
// threshold search; one-pass compaction; softmax with key-decoded sims.
__global__ __launch_bounds__(512) void k_select(const uint2* __restrict__ cand,
                                                const float* __restrict__ h,
                                                float* __restrict__ out, int nAll) {
  __shared__ unsigned pkx[2048];   // [g][rl] u32, slot = g*8 + (rl ^ ((g>>2)&7))
  __shared__ unsigned pky[2048];
  __shared__ unsigned s_p[8][16];  // packed kept candidates per wave
  const int t = threadIdx.x;
  const int lane = t & 63, wid = t >> 6;
  const int r0 = blockIdx.x * 8;
  const int r = r0 + wid;          // this wave's row
  const unsigned long long ltmask = (1ull << lane) - 1ull;

  if (lane < 16) s_p[wid][lane] = 0;  // pads: key 0 -> sim -2 -> weight ~0

  // Stage: 4 passes x 512 threads; 8 consecutive rows per 64-B line.
  #pragma unroll
  for (int p = 0; p < 4; ++p) {
    const int g = p * 64 + (t >> 3);
    const int rl = t & 7;
    const uint2 q = cand[(size_t)g * nAll + r0 + rl];
    const int slot = g * 8 + (rl ^ ((g >> 2) & 7));
    pkx[slot] = q.x; pky[slot] = q.y;
  }
  __syncthreads();

  // Phase 1: 8 packed candidates per lane from LDS (2-way reads, free).
  unsigned pk[8];
  #pragma unroll
  for (int i = 0; i < 4; ++i) {
    const int g = i * 64 + lane;
    const int slot = g * 8 + (wid ^ ((g >> 2) & 7));
    pk[i * 2 + 0] = pkx[slot];
    pk[i * 2 + 1] = pky[slot];
  }
  const unsigned selfpat = (unsigned)(nAll - 1 - r);
  #pragma unroll
  for (int i = 0; i < 8; ++i) if ((pk[i] & 0xFFFFu) == selfpat) pk[i] = 0;

  // Phase 2: fixed-bounds branch-free binary search for largest t2 with
  // count(key16 >= t2) >= CAND_TARGET. key = sim+2 in [1,3] -> [0x3F80,0x4040].
  unsigned lo = 0x3F80u, hi = 0x4040u;
  #pragma unroll
  for (int it = 0; it < 8; ++it) {
    const unsigned mid = (lo + hi + 1) >> 1;
    int c = 0;
    #pragma unroll
    for (int i = 0; i < 8; ++i) c += __popcll(__ballot((pk[i] >> 16) >= mid));
    const bool ge = c >= CAND_TARGET;
    lo = ge ? mid : lo;
    hi = ge ? hi : mid - 1;
  }
  const unsigned t2 = lo;

  // Phase 3: one-pass compaction of entries >= t2 (self slots are 0 < t2).
  {
    int base = 0;
    #pragma unroll
    for (int i = 0; i < 8; ++i) {
      const bool p = (pk[i] >> 16) >= t2;
      const unsigned long long m = __ballot(p);
      const int pos = base + __popcll(m & ltmask);
      if (p && pos < NC_CAP) s_p[wid][pos] = pk[i];
      base += __popcll(m);
    }
  }

  // Phase 4: softmax over self (sim 1.0) + kept candidates, sims decoded
  // from keys: sim = as_float(key16 << 16) - 2. Pads: sim = -2 -> w ~ 0.
  float w[NC_CAP]; int cidx[NC_CAP];
  float z = 1.0f;
  #pragma unroll
  for (int i = 0; i < NC_CAP; ++i) {
    const unsigned p = s_p[wid][i];
    const float sim = __uint_as_float(p & 0xFFFF0000u) - 2.0f;
    w[i] = __expf(THETA * (sim - 1.0f));
    cidx[i] = nAll - 1 - (int)(p & 0xFFFFu);
    z += w[i];
  }
  const float rz = 1.0f / z;

  // Phase 5: fp32 weighted aggregation (self + 13 gathers, 512 B coalesced).
  const float2 hr = *(const float2*)(h + (size_t)r * 128 + lane * 2);
  float ax = hr.x, ay = hr.y;
  #pragma unroll
  for (int k = 0; k < NC_CAP; ++k) {
    const float2 hc = *(const float2*)(h + (size_t)cidx[k] * 128 + lane * 2);
    ax += w[k] * hc.x; ay += w[k] * hc.y;
  }
  float2 o2; o2.x = ax * rz; o2.y = ay * rz;
  *(float2*)(out + (size_t)r * 128 + lane * 2) = o2;
}

extern "C" void kernel_launch(void* const* d_in, const int* in_sizes, int n_in,
                              void* d_out, int out_size, void* d_ws, size_t ws_size,
                              hipStream_t stream) {
  const float* h = (const float*)d_in[0];
  float* out = (float*)d_out;
  const int N = in_sizes[0] / 128;  // 16384
  char* ws = (char*)d_ws;
  unsigned short* hnb = (unsigned short*)ws;         // N*128 bf16 = 4 MiB
  size_t off = ((size_t)N * 256 + 511) & ~(size_t)511;
  uint2* cand = (uint2*)(ws + off);                  // [G][N] uint2 = 32 MiB

  hipLaunchKernelGGL(k_norm, dim3((N + 3) / 4), dim3(256), 0, stream, h, hnb, N);
  hipLaunchKernelGGL(k_gemm, dim3(N / 128, N / 128), dim3(256), 0, stream, hnb, cand, N);
  hipLaunchKernelGGL(k_select, dim3(N / 8), dim3(512), 0, stream, cand, h, out, N);
}

// Round 12
// 151.834 us; speedup vs baseline: 2.3776x; 1.0869x over previous
//
#include <hip/hip_runtime.h>
#include <stdint.h>

typedef __attribute__((ext_vector_type(8))) short short8_t;
typedef __attribute__((ext_vector_type(4))) float f32x4_t;

#define THETA 12.0f
#define EPS 1e-8f
#define CAND_TARGET 11  // non-self candidates kept by threshold (need >= 9)
#define NC_CAP 13       // non-self candidate cap

__device__ __forceinline__ unsigned short f2bf(float f) {
  unsigned int u = __float_as_uint(f);
  u = (u + 0x7fffu + ((u >> 16) & 1u)) >> 16;
  return (unsigned short)u;
}
__device__ __forceinline__ unsigned umax_(unsigned a, unsigned b) { return a > b ? a : b; }
__device__ __forceinline__ unsigned sx(unsigned v, int m) {
  return (unsigned)__shfl_xor((int)v, m);
}
__device__ __forceinline__ void load_lds16(const void* g, void* l) {
  __builtin_amdgcn_global_load_lds((const __attribute__((address_space(1))) void*)g,
                                   (__attribute__((address_space(3))) void*)l, 16, 0, 0);
}

// K1: bf16 row-normalized copy. One wave per row.
__global__ __launch_bounds__(256) void k_norm(const float* __restrict__ h,
                                              unsigned short* __restrict__ hnb, int n) {
  const int row = blockIdx.x * 4 + (threadIdx.x >> 6);
  const int lane = threadIdx.x & 63;
  if (row >= n) return;
  const float2 hv = *(const float2*)(h + (size_t)row * 128 + lane * 2);
  float ss = hv.x * hv.x + hv.y * hv.y;
  #pragma unroll
  for (int o = 32; o > 0; o >>= 1) ss += __shfl_xor(ss, o);
  const float rn = 1.0f / fmaxf(sqrtf(ss), EPS);
  const unsigned int b0 = f2bf(hv.x * rn), b1 = f2bf(hv.y * rn);
  *(unsigned int*)(hnb + (size_t)row * 128 + lane * 2) = b0 | (b1 << 16);
}

// K2 v12: 128x128 tile, K split into two 64-wide halves, single-buffered
// 32 KB LDS -> 4 blocks/CU. acc init = 2.0f so acc = sim+2 is positive ->
// raw IEEE bits monotone. Epilogue: top-1 per 64-col group (one u32 per
// (row, group)): packed (key16<<16)|(N-1-col), 16-way umax tree + 2 shfl.
__global__ __launch_bounds__(256, 4) void k_gemm(const unsigned short* __restrict__ hnb,
                                                 unsigned* __restrict__ cand, int nAll) {
  __shared__ __align__(16) char lds[32768];
  char* As = lds;            // [128 rows][128 B] bf16, XOR-swizzled
  char* Bs = lds + 16384;
  const int tid = threadIdx.x;
  const int wid = tid >> 6, lane = tid & 63;
  const int l15 = lane & 15, lhi = lane >> 4;
  const int wr = wid >> 1, wc = wid & 1;

  const char* gA = (const char*)hnb + (size_t)(blockIdx.y * 128) * 256;
  const char* gB = (const char*)hnb + (size_t)(blockIdx.x * 128) * 256;

  f32x4_t acc[4][4];
  #pragma unroll
  for (int m = 0; m < 4; ++m)
    #pragma unroll
    for (int nn = 0; nn < 4; ++nn)
      acc[m][nn] = (f32x4_t){2.0f, 2.0f, 2.0f, 2.0f};

  #pragma unroll
  for (int ks = 0; ks < 2; ++ks) {
    // Stage this K-half (linear LDS dest, inverse-swizzled source).
    #pragma unroll
    for (int it = 0; it < 4; ++it) {
      const int ob = it * 4096 + tid * 16;
      const int row = ob >> 7;
      const int sbc = (ob & 127) ^ ((row & 7) << 4);
      const int ldso = it * 4096 + wid * 1024;  // wave-uniform base
      load_lds16(gA + row * 256 + ks * 128 + sbc, As + ldso);
      load_lds16(gB + row * 256 + ks * 128 + sbc, Bs + ldso);
    }
    __syncthreads();
    #pragma unroll
    for (int kk = 0; kk < 2; ++kk) {
      short8_t af[4], bfr[4];
      #pragma unroll
      for (int m = 0; m < 4; ++m) {
        const int row = wr * 64 + m * 16 + l15;
        const int addr = row * 128 + ((kk * 64 + lhi * 16) ^ ((row & 7) << 4));
        af[m] = *(const short8_t*)(As + addr);
      }
      #pragma unroll
      for (int nn = 0; nn < 4; ++nn) {
        const int row = wc * 64 + nn * 16 + l15;
        const int addr = row * 128 + ((kk * 64 + lhi * 16) ^ ((row & 7) << 4));
        bfr[nn] = *(const short8_t*)(Bs + addr);
      }
      #pragma unroll
      for (int m = 0; m < 4; ++m)
        #pragma unroll
        for (int nn = 0; nn < 4; ++nn)
          acc[m][nn] = __builtin_amdgcn_mfma_f32_16x16x32_bf16(bfr[nn], af[m], acc[m][nn], 0, 0, 0);
    }
    if (ks == 0) __syncthreads();  // protect buffers before half-2 staging
  }

  // Epilogue: lane's 16 values for row wr*64+m*16+l15 are cols
  // bx*128 + wc*64 + nn*16 + lhi*4 + j -> all in group g = bx*2 + wc.
  const unsigned ccbase = (unsigned)(nAll - 1 - (blockIdx.x * 128 + wc * 64 + lhi * 4));
  unsigned ccnj[16];
  #pragma unroll
  for (int nn = 0; nn < 4; ++nn)
    #pragma unroll
    for (int j = 0; j < 4; ++j) ccnj[nn * 4 + j] = ccbase - (unsigned)(nn * 16 + j);
  #pragma unroll
  for (int m = 0; m < 4; ++m) {
    unsigned a01 = 0, a23 = 0;  // two chains for ILP, then merge
    #pragma unroll
    for (int nn = 0; nn < 2; ++nn)
      #pragma unroll
      for (int j = 0; j < 4; ++j)
        a01 = umax_(a01, (__float_as_uint(acc[m][nn][j]) & 0xFFFF0000u) | ccnj[nn * 4 + j]);
    #pragma unroll
    for (int nn = 2; nn < 4; ++nn)
      #pragma unroll
      for (int j = 0; j < 4; ++j)
        a23 = umax_(a23, (__float_as_uint(acc[m][nn][j]) & 0xFFFF0000u) | ccnj[nn * 4 + j]);
    unsigned a = umax_(a01, a23);
    a = umax_(a, sx(a, 16)); a = umax_(a, sx(a, 32));
    if (lhi == 0) {
      const int grow = blockIdx.y * 128 + wr * 64 + m * 16 + l15;
      const int g = blockIdx.x * 2 + wc;
      cand[(size_t)g * nAll + grow] = a;
    }
  }
}

// K3 v12: 512-thread block = 8 waves = 8 consecutive rows. Coalesced staging
// of cand[*][r0..r0+7] (8 KB) into swizzled LDS; 4 keys/lane; fixed-bounds
// branch-free 8-iter threshold search; one-pass compaction; softmax with
// key-decoded sims + self at weight 1; fp32 aggregation.
__global__ __launch_bounds__(512) void k_select(const unsigned* __restrict__ cand,
                                                const float* __restrict__ h,
                                                float* __restrict__ out, int nAll) {
  __shared__ unsigned pkx[2048];   // [g][rl] u32, slot = g*8 + (rl ^ ((g>>2)&7))
  __shared__ unsigned s_p[8][16];  // packed kept candidates per wave
  const int t = threadIdx.x;
  const int lane = t & 63, wid = t >> 6;
  const int r0 = blockIdx.x * 8;
  const int r = r0 + wid;          // this wave's row
  const unsigned long long ltmask = (1ull << lane) - 1ull;

  if (lane < 16) s_p[wid][lane] = 0;  // pads: key 0 -> sim -2 -> weight ~0

  // Stage: 4 passes x 512 threads; 8 consecutive rows = 32 B per group.
  #pragma unroll
  for (int p = 0; p < 4; ++p) {
    const int idx = p * 512 + t;
    const int g = idx >> 3, rl = idx & 7;
    const unsigned q = cand[(size_t)g * nAll + r0 + rl];
    pkx[g * 8 + (rl ^ ((g >> 2) & 7))] = q;
  }
  __syncthreads();

  // Phase 1: 4 group-max candidates per lane from LDS (2-way reads, free).
  unsigned pk[4];
  #pragma unroll
  for (int i = 0; i < 4; ++i) {
    const int g = i * 64 + lane;
    pk[i] = pkx[g * 8 + (wid ^ ((g >> 2) & 7))];
  }
  const unsigned selfpat = (unsigned)(nAll - 1 - r);
  #pragma unroll
  for (int i = 0; i < 4; ++i) if ((pk[i] & 0xFFFFu) == selfpat) pk[i] = 0;

  // Phase 2: fixed-bounds branch-free binary search for largest t2 with
  // count(key16 >= t2) >= CAND_TARGET. key = sim+2 in [1,3] -> [0x3F80,0x4040]
  // (count(>=0x3F80) = 255 non-self groups >= TARGET; count(>=0x4041) = 0).
  unsigned lo = 0x3F80u, hi = 0x4040u;
  #pragma unroll
  for (int it = 0; it < 8; ++it) {
    const unsigned mid = (lo + hi + 1) >> 1;
    int c = 0;
    #pragma unroll
    for (int i = 0; i < 4; ++i) c += __popcll(__ballot((pk[i] >> 16) >= mid));
    const bool ge = c >= CAND_TARGET;
    lo = ge ? mid : lo;
    hi = ge ? hi : mid - 1;
  }
  const unsigned t2 = lo;

  // Phase 3: one-pass compaction of entries >= t2 (self slots are 0 < t2).
  // Strict > t2 count <= 10 by search invariant; ties fill to NC_CAP.
  {
    int base = 0;
    #pragma unroll
    for (int i = 0; i < 4; ++i) {
      const bool p = (pk[i] >> 16) >= t2;
      const unsigned long long m = __ballot(p);
      const int pos = base + __popcll(m & ltmask);
      if (p && pos < NC_CAP) s_p[wid][pos] = pk[i];
      base += __popcll(m);
    }
  }

  // Phase 4: softmax over self (sim 1.0) + kept candidates, sims decoded
  // from keys: sim = as_float(key16 << 16) - 2. Pads: sim = -2 -> w ~ 0.
  float w[NC_CAP]; int cidx[NC_CAP];
  float z = 1.0f;
  #pragma unroll
  for (int i = 0; i < NC_CAP; ++i) {
    const unsigned p = s_p[wid][i];
    const float sim = __uint_as_float(p & 0xFFFF0000u) - 2.0f;
    w[i] = __expf(THETA * (sim - 1.0f));
    cidx[i] = nAll - 1 - (int)(p & 0xFFFFu);
    z += w[i];
  }
  const float rz = 1.0f / z;

  // Phase 5: fp32 weighted aggregation (self + 13 gathers, 512 B coalesced).
  const float2 hr = *(const float2*)(h + (size_t)r * 128 + lane * 2);
  float ax = hr.x, ay = hr.y;
  #pragma unroll
  for (int k = 0; k < NC_CAP; ++k) {
    const float2 hc = *(const float2*)(h + (size_t)cidx[k] * 128 + lane * 2);
    ax += w[k] * hc.x; ay += w[k] * hc.y;
  }
  float2 o2; o2.x = ax * rz; o2.y = ay * rz;
  *(float2*)(out + (size_t)r * 128 + lane * 2) = o2;
}

extern "C" void kernel_launch(void* const* d_in, const int* in_sizes, int n_in,
                              void* d_out, int out_size, void* d_ws, size_t ws_size,
                              hipStream_t stream) {
  const float* h = (const float*)d_in[0];
  float* out = (float*)d_out;
  const int N = in_sizes[0] / 128;  // 16384
  char* ws = (char*)d_ws;
  unsigned short* hnb = (unsigned short*)ws;         // N*128 bf16 = 4 MiB
  size_t off = ((size_t)N * 256 + 511) & ~(size_t)511;
  unsigned* cand = (unsigned*)(ws + off);            // [G][N] u32 = 16 MiB

  hipLaunchKernelGGL(k_norm, dim3((N + 3) / 4), dim3(256), 0, stream, h, hnb, N);
  hipLaunchKernelGGL(k_gemm, dim3(N / 128, N / 128), dim3(256), 0, stream, hnb, cand, N);
  hipLaunchKernelGGL(k_select, dim3(N / 8), dim3(512), 0, stream, cand, h, out, N);
}